// Round 13
// baseline (1774.801 us; speedup 1.0000x reference)
//
#include <hip/hip_runtime.h>
#include <hip/hip_fp16.h>

#define NN 4096
#define IN_DIM 512
#define HID 256
#define OUT_DIM 128
#define MAXDEG 192
#define NBLK 1024
#define INV_GAMMA (1.0f / 6.0f)
#define LAM 0.11111111111111116f   // 1/0.9 - 1
#define PROP_STEPS 10

// ---------------------------------------------------------------------------
// Dense A scan (float4): per-row adjacency list, degree, D=rowsum+1, 1/D, 1/sqrt(D).
__global__ void k_analyze(const float* __restrict__ A, unsigned short* __restrict__ cols,
                          int* __restrict__ deg, float* __restrict__ DsqInv,
                          float* __restrict__ Dinv) {
    int wid = threadIdx.x >> 6, lane = threadIdx.x & 63;
    int row = blockIdx.x * 4 + wid;
    const float4* Ar = (const float4*)(A + (size_t)row * NN);
    unsigned short* crow = cols + (size_t)row * MAXDEG;
    int cnt = 0;
    float fsum = 0.f;
    for (int it = 0; it < NN / 256; ++it) {
        float4 v = Ar[it * 64 + lane];
        fsum += (v.x + v.y) + (v.z + v.w);
        int colbase = (it * 64 + lane) * 4;
        float comp[4] = {v.x, v.y, v.z, v.w};
#pragma unroll
        for (int c = 0; c < 4; ++c) {
            bool nz = (comp[c] != 0.f);
            unsigned long long m = __ballot(nz);
            if (nz) {
                int off = cnt + __popcll(m & ((1ull << lane) - 1ull));
                if (off < MAXDEG) crow[off] = (unsigned short)(colbase + c);
            }
            cnt += __popcll(m);
        }
    }
#pragma unroll
    for (int m = 1; m < 64; m <<= 1) fsum += __shfl_xor(fsum, m);
    if (lane == 0) {
        float D = fsum + 1.0f;
        deg[row] = cnt < MAXDEG ? cnt : MAXDEG;
        DsqInv[row] = 1.0f / sqrtf(D);
        Dinv[row] = 1.0f / D;
    }
}

// ---------------------------------------------------------------------------
// Fused MLP (unchanged round-8 structure; X0 written as fp16).
__global__ __launch_bounds__(256) void k_mlp(const float* __restrict__ F,
                      const float* __restrict__ W1, const float* __restrict__ b1,
                      const float* __restrict__ W2, const float* __restrict__ b2,
                      const float* __restrict__ DsqInv,
                      float* __restrict__ F0, __half* __restrict__ Xh0) {
    __shared__ __align__(16) float sF[8 * IN_DIM];   // 16 KB
    __shared__ __align__(16) float sW[32 * 256];     // 32 KB
    __shared__ __align__(16) float sH[8 * HID];      // 8 KB
    int r0 = blockIdx.x * 8;
    int t = threadIdx.x;
    float4* sF4 = (float4*)sF;
    float4* sW4 = (float4*)sW;
#pragma unroll
    for (int i = 0; i < 4; ++i) {
        int idx = i * 256 + t;
        int r = idx >> 7, q = idx & 127;
        sF4[r * 128 + q] = *(const float4*)&F[(size_t)(r0 + r) * IN_DIM + 4 * q];
    }
    {   // layer 1: thread = (4 cols, 2 rows)
        int cq = t & 63, rg = t >> 6;
        float4 accA = make_float4(0.f, 0.f, 0.f, 0.f);
        float4 accB = make_float4(0.f, 0.f, 0.f, 0.f);
        for (int kt = 0; kt < IN_DIM / 32; ++kt) {
            __syncthreads();
#pragma unroll
            for (int i = 0; i < 8; ++i) {     // stage W1 tile [32][256]
                int idx = i * 256 + t;
                int kr = idx >> 6, q = idx & 63;
                sW4[kr * 64 + q] = *(const float4*)&W1[(size_t)(kt * 32 + kr) * HID + 4 * q];
            }
            __syncthreads();
#pragma unroll
            for (int g4 = 0; g4 < 8; ++g4) {
                float4 w0 = sW4[(4 * g4 + 0) * 64 + cq];
                float4 w1 = sW4[(4 * g4 + 1) * 64 + cq];
                float4 w2 = sW4[(4 * g4 + 2) * 64 + cq];
                float4 w3 = sW4[(4 * g4 + 3) * 64 + cq];
                float4 fA = sF4[(2 * rg) * 128 + kt * 8 + g4];
                float4 fB = sF4[(2 * rg + 1) * 128 + kt * 8 + g4];
                accA.x = fmaf(fA.x, w0.x, accA.x); accA.y = fmaf(fA.x, w0.y, accA.y);
                accA.z = fmaf(fA.x, w0.z, accA.z); accA.w = fmaf(fA.x, w0.w, accA.w);
                accA.x = fmaf(fA.y, w1.x, accA.x); accA.y = fmaf(fA.y, w1.y, accA.y);
                accA.z = fmaf(fA.y, w1.z, accA.z); accA.w = fmaf(fA.y, w1.w, accA.w);
                accA.x = fmaf(fA.z, w2.x, accA.x); accA.y = fmaf(fA.z, w2.y, accA.y);
                accA.z = fmaf(fA.z, w2.z, accA.z); accA.w = fmaf(fA.z, w2.w, accA.w);
                accA.x = fmaf(fA.w, w3.x, accA.x); accA.y = fmaf(fA.w, w3.y, accA.y);
                accA.z = fmaf(fA.w, w3.z, accA.z); accA.w = fmaf(fA.w, w3.w, accA.w);
                accB.x = fmaf(fB.x, w0.x, accB.x); accB.y = fmaf(fB.x, w0.y, accB.y);
                accB.z = fmaf(fB.x, w0.z, accB.z); accB.w = fmaf(fB.x, w0.w, accB.w);
                accB.x = fmaf(fB.y, w1.x, accB.x); accB.y = fmaf(fB.y, w1.y, accB.y);
                accB.z = fmaf(fB.y, w1.z, accB.z); accB.w = fmaf(fB.y, w1.w, accB.w);
                accB.x = fmaf(fB.z, w2.x, accB.x); accB.y = fmaf(fB.z, w2.y, accB.y);
                accB.z = fmaf(fB.z, w2.z, accB.z); accB.w = fmaf(fB.z, w2.w, accB.w);
                accB.x = fmaf(fB.w, w3.x, accB.x); accB.y = fmaf(fB.w, w3.y, accB.y);
                accB.z = fmaf(fB.w, w3.z, accB.z); accB.w = fmaf(fB.w, w3.w, accB.w);
            }
        }
        float4 b = *(const float4*)&b1[4 * cq];
        float4 ha, hb;
        ha.x = fmaxf(accA.x + b.x, 0.f); ha.y = fmaxf(accA.y + b.y, 0.f);
        ha.z = fmaxf(accA.z + b.z, 0.f); ha.w = fmaxf(accA.w + b.w, 0.f);
        hb.x = fmaxf(accB.x + b.x, 0.f); hb.y = fmaxf(accB.y + b.y, 0.f);
        hb.z = fmaxf(accB.z + b.z, 0.f); hb.w = fmaxf(accB.w + b.w, 0.f);
        *(float4*)&sH[(2 * rg) * HID + 4 * cq] = ha;
        *(float4*)&sH[(2 * rg + 1) * HID + 4 * cq] = hb;
    }
    {   // layer 2: thread = (1 col, 4 rows)
        int c = t & 127, half = t >> 7;
        float acc2[4] = {0.f, 0.f, 0.f, 0.f};
        for (int kt = 0; kt < HID / 32; ++kt) {
            __syncthreads();
#pragma unroll
            for (int i = 0; i < 4; ++i) {     // stage W2 tile [32][128]
                int idx = i * 256 + t;
                int kr = idx >> 5, q = idx & 31;
                sW4[kr * 32 + q] = *(const float4*)&W2[(size_t)(kt * 32 + kr) * OUT_DIM + 4 * q];
            }
            __syncthreads();
#pragma unroll
            for (int kk = 0; kk < 32; ++kk) {
                int k = kt * 32 + kk;
                float w = sW[kk * 128 + c];
#pragma unroll
                for (int r = 0; r < 4; ++r)
                    acc2[r] = fmaf(sH[(half * 4 + r) * HID + k], w, acc2[r]);
            }
        }
        float b = b2[c];
#pragma unroll
        for (int r = 0; r < 4; ++r) {
            int row = r0 + half * 4 + r;
            float v = acc2[r] + b;
            F0[(size_t)row * OUT_DIM + c] = v;
            Xh0[(size_t)row * OUT_DIM + c] = __float2half(v * DsqInv[row]);
        }
    }
}

// ---------------------------------------------------------------------------
// Software grid barrier (sense-reversing, device-scope).  All NBLK blocks are
// co-resident by construction (__launch_bounds__(256,4) -> 4 blocks/CU x 256
// CUs = 1024 = grid).  Bounded spin: breaks (wrong answer, no hang) if the
// co-residency assumption were ever violated.
__device__ __forceinline__ void grid_barrier(unsigned* cnt, unsigned* gen) {
    __syncthreads();
    if (threadIdx.x == 0) {
        __threadfence();   // release: writeback this XCD's dirty L2
        unsigned my = __hip_atomic_load(gen, __ATOMIC_ACQUIRE, __HIP_MEMORY_SCOPE_AGENT);
        unsigned a = __hip_atomic_fetch_add(cnt, 1u, __ATOMIC_ACQ_REL, __HIP_MEMORY_SCOPE_AGENT);
        if (a == (unsigned)(NBLK - 1)) {
            __hip_atomic_store(cnt, 0u, __ATOMIC_RELAXED, __HIP_MEMORY_SCOPE_AGENT);
            __hip_atomic_fetch_add(gen, 1u, __ATOMIC_RELEASE, __HIP_MEMORY_SCOPE_AGENT);
        } else {
            int guard = 0;
            while (__hip_atomic_load(gen, __ATOMIC_ACQUIRE, __HIP_MEMORY_SCOPE_AGENT) == my) {
                __builtin_amdgcn_s_sleep(2);
                if (++guard > (1 << 24)) break;
            }
        }
        __threadfence();   // acquire: invalidate this CU's L1 / XCD L2
    }
    __syncthreads();
}

// ---------------------------------------------------------------------------
// ALL 10 IRLS steps, persistent kernel + software grid sync.  1024 blocks
// (exactly 4/CU), 256 thr.  Wave per row, 8-lane group per edge, fp16 X
// gather, prefetch depth 1.  sCols persists in LDS across all steps.
__global__ __launch_bounds__(256, 4) void k_prop_all(
                       const float* __restrict__ F0,
                       const unsigned short* __restrict__ cols, const int* __restrict__ deg,
                       const float* __restrict__ DsqInv, const float* __restrict__ Dinv,
                       __half* __restrict__ XA, __half* __restrict__ XB,
                       float* __restrict__ sqA, float* __restrict__ sqB,
                       float* __restrict__ out, unsigned* __restrict__ bar) {
    __shared__ unsigned short sCols[4][MAXDEG];
    __shared__ __align__(16) float sPart[4][8][136];
    union F4H { float4 f4; __half2 h2[4]; };
    int t = threadIdx.x;
    int wid = t >> 6, lane = t & 63;
    int row = blockIdx.x * 4 + wid;
    int g = lane >> 3, oc = lane & 7;
    int dg = deg[row];
    float dsi = DsqInv[row], di = Dinv[row];
    for (int e = lane; e < dg; e += 64) sCols[wid][e] = cols[(size_t)row * MAXDEG + e];
    // prologue: sq of initial X (XA)
    {
        float2 x = __half22float2(((const __half2*)XA)[row * 64 + lane]);
        float s = x.x * x.x + x.y * x.y;
#pragma unroll
        for (int m = 1; m < 64; m <<= 1) s += __shfl_xor(s, m);
        if (lane == 0) sqA[row] = s;
    }
    grid_barrier(&bar[0], &bar[1]);

    __half* Xc = XA; __half* Xn = XB;
    float* sqc = sqA; float* sqn = sqB;
    for (int step = 0; step < PROP_STEPS; ++step) {
        bool fin = (step == PROP_STEPS - 1);
        float sqi = sqc[row];
        const float4* Xi4 = (const float4*)(Xc + (size_t)row * 128);
        float xi[16];
        {
            F4H u0, u1;
            u0.f4 = Xi4[oc];
            u1.f4 = Xi4[8 + oc];
#pragma unroll
            for (int k = 0; k < 4; ++k) {
                float2 f = __half22float2(u0.h2[k]);
                xi[2 * k] = f.x; xi[2 * k + 1] = f.y;
                float2 f2 = __half22float2(u1.h2[k]);
                xi[8 + 2 * k] = f2.x; xi[8 + 2 * k + 1] = f2.y;
            }
        }
        float acc[16];
#pragma unroll
        for (int k = 0; k < 16; ++k) acc[k] = 0.f;
        float qacc = 0.f;
        {
            int nch = (dg + 7) >> 3;
            int ec = (g < dg) ? g : (dg - 1);
            int j = (int)sCols[wid][ec];
            F4H u0, u1;
            const float4* Xj4 = (const float4*)(Xc + (size_t)j * 128);
            u0.f4 = Xj4[oc]; u1.f4 = Xj4[8 + oc];
            float sqj = sqc[j];
            for (int ch = 0; ch < nch; ++ch) {
                int en = (ch + 1) * 8 + g; en = (en < dg) ? en : (dg - 1);
                int jn = (int)sCols[wid][en];
                const float4* Xn4 = (const float4*)(Xc + (size_t)jn * 128);
                F4H n0, n1;
                n0.f4 = Xn4[oc]; n1.f4 = Xn4[8 + oc];
                float sqjn = sqc[jn];
                float cj[16];
#pragma unroll
                for (int k = 0; k < 4; ++k) {
                    float2 f = __half22float2(u0.h2[k]);
                    cj[2 * k] = f.x; cj[2 * k + 1] = f.y;
                    float2 f2 = __half22float2(u1.h2[k]);
                    cj[8 + 2 * k] = f2.x; cj[8 + 2 * k + 1] = f2.y;
                }
                float pA = 0.f, pB = 0.f;
#pragma unroll
                for (int k = 0; k < 8; ++k) {
                    pA = fmaf(xi[k], cj[k], pA);
                    pB = fmaf(xi[8 + k], cj[8 + k], pB);
                }
                float p = pA + pB;
                p += __shfl_xor(p, 1);
                p += __shfl_xor(p, 2);
                p += __shfl_xor(p, 4);
                float z = fmaxf(sqi + sqj - 2.f * p, 0.f);
                float w = fmaxf(1.f - sqrtf(z) * INV_GAMMA, 0.f);
                bool act = (ch * 8 + g) < dg;
                w = act ? w : 0.f;
                qacc += w;
#pragma unroll
                for (int k = 0; k < 16; ++k) acc[k] = fmaf(w, cj[k], acc[k]);
                u0 = n0; u1 = n1; sqj = sqjn;
            }
        }
        {
            float* part = &sPart[wid][g][0];
            *(float4*)&part[8 * oc]          = make_float4(acc[0], acc[1], acc[2], acc[3]);
            *(float4*)&part[8 * oc + 4]      = make_float4(acc[4], acc[5], acc[6], acc[7]);
            *(float4*)&part[64 + 8 * oc]     = make_float4(acc[8], acc[9], acc[10], acc[11]);
            *(float4*)&part[64 + 8 * oc + 4] = make_float4(acc[12], acc[13], acc[14], acc[15]);
            if (oc == 0) part[128] = qacc;
        }
        __syncthreads();
        int d0 = lane * 2;
        float accX = 0.f, accY = 0.f, qs = 0.f;
#pragma unroll
        for (int s = 0; s < 8; ++s) {
            float2 v = *(const float2*)&sPart[wid][s][d0];
            accX += v.x; accY += v.y;
            qs += sPart[wid][s][128];
        }
        float invQ = 1.f / (qs * di + LAM);
        float2 f0 = *(const float2*)&F0[(size_t)row * 128 + d0];
        float ox = (dsi * accX + LAM * f0.x) * invQ;
        float oy = (dsi * accY + LAM * f0.y) * invQ;
        if (fin) {
            *(float2*)&out[(size_t)row * 128 + d0] = make_float2(ox, oy);
        } else {
            float xx = ox * dsi, xy = oy * dsi;
            __half2 hx = __floats2half2_rn(xx, xy);
            ((__half2*)(Xn + (size_t)row * 128))[lane] = hx;
            float2 xr = __half22float2(hx);   // sq from rounded values
            float ss = xr.x * xr.x + xr.y * xr.y;
#pragma unroll
            for (int m = 1; m < 64; m <<= 1) ss += __shfl_xor(ss, m);
            if (lane == 0) sqn[row] = ss;
            grid_barrier(&bar[0], &bar[1]);
            __half* th = Xc; Xc = Xn; Xn = th;
            float* tf = sqc; sqc = sqn; sqn = tf;
            __syncthreads();
        }
    }
}

extern "C" void kernel_launch(void* const* d_in, const int* in_sizes, int n_in,
                              void* d_out, int out_size, void* d_ws, size_t ws_size,
                              hipStream_t stream) {
    const float *A = nullptr, *F = nullptr, *W1 = nullptr, *b1 = nullptr,
                *W2 = nullptr, *b2 = nullptr;
    for (int i = 0; i < n_in; i++) {
        switch (in_sizes[i]) {
            case NN * NN:        A  = (const float*)d_in[i]; break;
            case NN * IN_DIM:    F  = (const float*)d_in[i]; break;
            case IN_DIM * HID:   W1 = (const float*)d_in[i]; break;
            case HID:            b1 = (const float*)d_in[i]; break;
            case HID * OUT_DIM:  W2 = (const float*)d_in[i]; break;
            case OUT_DIM:        b2 = (const float*)d_in[i]; break;
            default: break;
        }
    }
    float* out = (float*)d_out;

    char* ws = (char*)d_ws;
    float* F0      = (float*)ws;  ws += (size_t)NN * OUT_DIM * 4;   // 2 MB
    __half* XhA    = (__half*)ws; ws += (size_t)NN * OUT_DIM * 2;   // 1 MB
    __half* XhB    = (__half*)ws; ws += (size_t)NN * OUT_DIM * 2;   // 1 MB
    float* DsqInv  = (float*)ws;  ws += (size_t)NN * 4;
    float* Dinv    = (float*)ws;  ws += (size_t)NN * 4;
    float* sqA     = (float*)ws;  ws += (size_t)NN * 4;
    float* sqB     = (float*)ws;  ws += (size_t)NN * 4;
    int*   deg     = (int*)ws;    ws += (size_t)NN * 4;
    unsigned short* cols = (unsigned short*)ws; ws += (size_t)NN * MAXDEG * 2; // 1.5 MB
    unsigned* bar  = (unsigned*)ws; ws += 64;   // barrier {count, generation}

    // d_ws is poisoned to 0xAA before every launch: barrier state MUST be zeroed.
    hipMemsetAsync(bar, 0, 64, stream);

    hipLaunchKernelGGL(k_analyze, dim3(NN / 4), dim3(256), 0, stream, A, cols, deg, DsqInv, Dinv);
    hipLaunchKernelGGL(k_mlp, dim3(NN / 8), dim3(256), 0, stream,
                       F, W1, b1, W2, b2, DsqInv, F0, XhA);
    hipLaunchKernelGGL(k_prop_all, dim3(NBLK), dim3(256), 0, stream,
                       F0, cols, deg, DsqInv, Dinv, XhA, XhB, sqA, sqB, out, bar);
}